// Round 2
// baseline (229.335 us; speedup 1.0000x reference)
//
#include <hip/hip_runtime.h>

#define TPB 256
#define EPB 16            // elements per block (16 lanes / element)
#define H1S 246           // padded row stride for h1 (245 used)
#define XS  260           // padded row stride for staged x (256 used)

// ---- d_ws float offsets ----
#define WQ1   0      // 65
#define WQ2   65     // 450
#define WR1Q  515    // 100
#define WR2Q  615    // 100
#define WCQ   715    // 64 (c1 @715, c2 @747)
#define WSB   779    // 474 folded BN (scale|bias per layer)
#define SMALL_N 1253
#define WQA1  1280   // 9800
#define WQA2  11080  // 9800
#define WQB1  20880  // 2100
#define WQB2  22980  // 2100  (total 25080 floats = 100320 B of ws)

// sb sub-offsets (relative to WSB): [scale[C] | bias[C]] per layer
#define SB_P1 0
#define SB_P2 10
#define SB_R1 30
#define SB_R2 50
#define SB_A1 70
#define SB_B1 210
#define SB_C1 270
#define SB_A2 272
#define SB_B2 412
#define SB_C2 472

// ---------------- prep: quantize weights + fold BN into ws ----------------
#define GFOLD(bn, C, OFF)                                                     \
  if (tid < (C)) {                                                            \
    float gg = (bn)[tid], bb = (bn)[(C) + tid];                               \
    float mm = (bn)[2 * (C) + tid], vv = (bn)[3 * (C) + tid];                 \
    float sc = gg / sqrtf(vv + 1e-5f);                                        \
    sbp[(OFF) + tid] = sc;                                                    \
    sbp[(OFF) + (C) + tid] = bb - mm * sc;                                    \
  }

extern "C" __global__ __launch_bounds__(256)
void prep(const float* __restrict__ w1,  const float* __restrict__ bnp1,
          const float* __restrict__ w2,  const float* __restrict__ bnp2,
          const float* __restrict__ wr1, const float* __restrict__ bnr1,
          const float* __restrict__ wr2, const float* __restrict__ bnr2,
          const float* __restrict__ wa1, const float* __restrict__ bna1,
          const float* __restrict__ wb1, const float* __restrict__ bnb1,
          const float* __restrict__ wc1, const float* __restrict__ bnc1,
          const float* __restrict__ wa2, const float* __restrict__ bna2,
          const float* __restrict__ wb2, const float* __restrict__ bnb2,
          const float* __restrict__ wc2, const float* __restrict__ bnc2,
          float* __restrict__ ws)
{
  __shared__ float s_red[4];
  const int tid = threadIdx.x;
  const int b = blockIdx.x;

  if (b == 10) {  // fold all BN params
    float* sbp = ws + WSB;
    GFOLD(bnp1, 5, SB_P1)  GFOLD(bnp2, 10, SB_P2)
    GFOLD(bnr1, 10, SB_R1) GFOLD(bnr2, 10, SB_R2)
    GFOLD(bna1, 70, SB_A1) GFOLD(bnb1, 30, SB_B1) GFOLD(bnc1, 1, SB_C1)
    GFOLD(bna2, 70, SB_A2) GFOLD(bnb2, 30, SB_B2) GFOLD(bnc2, 1, SB_C2)
    return;
  }

  const float* src; float* dst; int n;
  switch (b) {
    case 0: src = w1;  dst = ws + WQ1;      n = 65;   break;
    case 1: src = w2;  dst = ws + WQ2;      n = 450;  break;
    case 2: src = wr1; dst = ws + WR1Q;     n = 100;  break;
    case 3: src = wr2; dst = ws + WR2Q;     n = 100;  break;
    case 4: src = wa1; dst = ws + WQA1;     n = 9800; break;
    case 5: src = wb1; dst = ws + WQB1;     n = 2100; break;
    case 6: src = wc1; dst = ws + WCQ;      n = 30;   break;
    case 7: src = wa2; dst = ws + WQA2;     n = 9800; break;
    case 8: src = wb2; dst = ws + WQB2;     n = 2100; break;
    default:src = wc2; dst = ws + WCQ + 32; n = 30;   break;
  }

  float m = 0.f;
  for (int i = tid; i < n; i += 256) m = fmaxf(m, fabsf(src[i]));
#pragma unroll
  for (int off = 32; off > 0; off >>= 1)
    m = fmaxf(m, __shfl_down(m, off, 64));
  if ((tid & 63) == 0) s_red[tid >> 6] = m;
  __syncthreads();
  m = fmaxf(fmaxf(s_red[0], s_red[1]), fmaxf(s_red[2], s_red[3]));

  // exactly the reference: s = amax/127; q = round(clip(w/s,-127,127))*s
  float s = m / 127.0f;
  for (int i = tid; i < n; i += 256) {
    float w = src[i];
    dst[i] = rintf(fminf(fmaxf(w / s, -127.f), 127.f)) * s;
  }
}

// ---------------- main pipeline ----------------
extern "C" __global__ __launch_bounds__(TPB, 4)
void taunet(const float* __restrict__ x, const float* __restrict__ ws,
            float* __restrict__ out, int B)
{
  // s_xb overlay: phase 1 holds staged x (stride XS=260/elem, 4160 used);
  // after P1 it becomes h2[16][140] (offset 0) and t1[16][140] (offset 2240).
  __shared__ __align__(16) float s_h1[EPB * H1S];   // pre1 out; later 70-vec
  __shared__ __align__(16) float s_xb[4480];
  __shared__ __align__(16) float s_small[SMALL_N];

  const int tid = threadIdx.x;
  const int g = tid >> 4;     // element within block
  const int l = tid & 15;     // lane within element group
  const int elem = blockIdx.x * EPB + g;

  // stage small quantized weights + folded BN (block-cooperative)
  for (int i = tid; i < SMALL_N; i += TPB) s_small[i] = ws[i];

  // stage x per-wave (each wave stages its own 4 elements; coalesced float4)
  {
    const int wv = tid >> 6, ln = tid & 63;
    const float4* xb = (const float4*)x;
#pragma unroll
    for (int it = 0; it < 4; ++it) {
      int e = 4 * wv + it;
      int ge = blockIdx.x * EPB + e;
      if (ge < B) {
        float4 v = xb[ge * 64 + ln];
        *(float4*)&s_xb[e * XS + ln * 4] = v;
      }
    }
  }
  __syncthreads();   // for s_small (x is wave-local already)

  const float* sb = &s_small[WSB];

  // ---- P1: pre1 (Cin=1, K=13, stride 5) -> h1[5][49] ----
  {
    const float* xe = &s_xb[g * XS];
#pragma unroll
    for (int rep = 0; rep < 4; ++rep) {
      int p = l + 16 * rep;
      bool act = p < 49;
      int ps = act ? p : 0;
      float win[13];
#pragma unroll
      for (int k = 0; k < 13; ++k) win[k] = xe[5 * ps + k];
#pragma unroll
      for (int ci = 0; ci < 5; ++ci) {
        float a0 = 0.f, a1 = 0.f;
#pragma unroll
        for (int k = 0; k < 13; ++k) {
          float d = fabsf(win[k] - s_small[WQ1 + ci * 13 + k]);
          if (k & 1) a1 += d; else a0 += d;
        }
        float v = fmaxf(fmaf(-(a0 + a1), sb[SB_P1 + ci], sb[SB_P1 + 5 + ci]), 0.f);
        if (act) s_h1[g * H1S + ci * 49 + ps] = v;
      }
    }
  }
  __syncthreads();   // x region dead everywhere; s_xb becomes h2/t1

  // ---- P2: pre2 (Cin=5, K=9, stride 3) -> h2[10][14]; lane = ow ----
  {
    int ow = (l < 14) ? l : 0;
    const float* h1b = &s_h1[g * H1S];
#pragma unroll
    for (int co = 0; co < 10; ++co) {
      float a0 = 0.f, a1 = 0.f;
#pragma unroll
      for (int ci = 0; ci < 5; ++ci)
#pragma unroll
        for (int k = 0; k < 9; ++k) {
          float d = fabsf(h1b[ci * 49 + 3 * ow + k] - s_small[WQ2 + co * 45 + ci * 9 + k]);
          if ((ci * 9 + k) & 1) a1 += d; else a0 += d;
        }
      float v = fmaxf(fmaf(-(a0 + a1), sb[SB_P2 + co], sb[SB_P2 + 10 + co]), 0.f);
      if (l < 14) s_xb[g * 140 + co * 14 + l] = v;
    }
  }
  // (wave-internal LDS RAW from here on — no barriers needed)

  // ---- P3: r1 (10x10, K=1) + relu -> t1 ----
#pragma unroll
  for (int j = 0; j < 9; ++j) {
    int idx = l + 16 * j;
    if (idx < 140) {
      int co = idx / 14, ow = idx % 14;
      float a0 = 0.f, a1 = 0.f;
#pragma unroll
      for (int ci = 0; ci < 10; ++ci) {
        float d = fabsf(s_xb[g * 140 + ci * 14 + ow] - s_small[WR1Q + co * 10 + ci]);
        if (ci & 1) a1 += d; else a0 += d;
      }
      s_xb[2240 + g * 140 + idx] =
          fmaxf(fmaf(-(a0 + a1), sb[SB_R1 + co], sb[SB_R1 + 10 + co]), 0.f);
    }
  }

  // ---- P4: r2 (no relu) + residual, h = relu(t2 + h2), in place ----
#pragma unroll
  for (int j = 0; j < 9; ++j) {
    int idx = l + 16 * j;
    if (idx < 140) {
      int co = idx / 14, ow = idx % 14;
      float a0 = 0.f, a1 = 0.f;
#pragma unroll
      for (int ci = 0; ci < 10; ++ci) {
        float d = fabsf(s_xb[2240 + g * 140 + ci * 14 + ow] - s_small[WR2Q + co * 10 + ci]);
        if (ci & 1) a1 += d; else a0 += d;
      }
      float t2 = fmaf(-(a0 + a1), sb[SB_R2 + co], sb[SB_R2 + 10 + co]);
      s_xb[g * 140 + idx] = fmaxf(t2 + s_xb[g * 140 + idx], 0.f);
    }
  }

  // ---- two output branches ----
  for (int br = 0; br < 2; ++br) {
    const float* qa = ws + (br ? WQA2 : WQA1);
    const float* qb = ws + (br ? WQB2 : WQB1);
    const int sbA = br ? SB_A2 : SB_A1;
    const int sbB = br ? SB_B2 : SB_B1;
    const int sbC = br ? SB_C2 : SB_C1;
    const float* hb = &s_xb[g * 140];

    // o?a: 70x140, weights straight from L2 (row broadcast across groups)
    for (int pss = 0; pss < 5; ++pss) {
      int cl = l + 16 * pss;
      bool act = cl < 70;
      int cls = act ? cl : 0;
      const float4* w4p = (const float4*)&qa[cls * 140];
      float a0 = 0.f, a1 = 0.f, a2 = 0.f, a3 = 0.f;
#pragma unroll
      for (int cb = 0; cb < 35; ++cb) {
        float4 h4 = *(const float4*)&hb[cb * 4];
        float4 w4 = w4p[cb];
        a0 += fabsf(h4.x - w4.x);
        a1 += fabsf(h4.y - w4.y);
        a2 += fabsf(h4.z - w4.z);
        a3 += fabsf(h4.w - w4.w);
      }
      if (act) {
        float sad = (a0 + a1) + (a2 + a3);
        s_h1[g * H1S + cl] = fmaxf(fmaf(-sad, sb[sbA + cl], sb[sbA + 70 + cl]), 0.f);
      }
    }

    // o?b: 30x70 -> t1[0..29]
#pragma unroll
    for (int pss = 0; pss < 2; ++pss) {
      int co = l + 16 * pss;
      bool act = co < 30;
      int cos = act ? co : 0;
      const float2* wr = (const float2*)&qb[cos * 70];
      const float* h70 = &s_h1[g * H1S];
      float a0 = 0.f, a1 = 0.f;
#pragma unroll
      for (int ci = 0; ci < 35; ++ci) {
        float2 w2v = wr[ci];
        a0 += fabsf(h70[2 * ci]     - w2v.x);
        a1 += fabsf(h70[2 * ci + 1] - w2v.y);
      }
      if (act)
        s_xb[2240 + g * 140 + cos] =
            fmaxf(fmaf(-(a0 + a1), sb[sbB + cos], sb[sbB + 30 + cos]), 0.f);
    }

    // o?c: 1x30 -> out
    if (l == 0 && elem < B) {
      const float* t30 = &s_xb[2240 + g * 140];
      float a0 = 0.f, a1 = 0.f;
#pragma unroll
      for (int ci = 0; ci < 30; ci += 2) {
        a0 += fabsf(t30[ci]     - s_small[WCQ + br * 32 + ci]);
        a1 += fabsf(t30[ci + 1] - s_small[WCQ + br * 32 + ci + 1]);
      }
      out[br * B + elem] = fmaxf(fmaf(-(a0 + a1), sb[sbC], sb[sbC + 1]), 0.f);
    }
  }
}

extern "C" void kernel_launch(void* const* d_in, const int* in_sizes, int n_in,
                              void* d_out, int out_size, void* d_ws, size_t ws_size,
                              hipStream_t stream) {
  const float* x    = (const float*)d_in[0];
  const float* w1   = (const float*)d_in[1];
  const float* bnp1 = (const float*)d_in[2];
  const float* w2   = (const float*)d_in[3];
  const float* bnp2 = (const float*)d_in[4];
  const float* wr1  = (const float*)d_in[5];
  const float* bnr1 = (const float*)d_in[6];
  const float* wr2  = (const float*)d_in[7];
  const float* bnr2 = (const float*)d_in[8];
  const float* wa1  = (const float*)d_in[9];
  const float* bna1 = (const float*)d_in[10];
  const float* wb1  = (const float*)d_in[11];
  const float* bnb1 = (const float*)d_in[12];
  const float* wc1  = (const float*)d_in[13];
  const float* bnc1 = (const float*)d_in[14];
  const float* wa2  = (const float*)d_in[15];
  const float* bna2 = (const float*)d_in[16];
  const float* wb2  = (const float*)d_in[17];
  const float* bnb2 = (const float*)d_in[18];
  const float* wc2  = (const float*)d_in[19];
  const float* bnc2 = (const float*)d_in[20];

  float* ws = (float*)d_ws;
  int B = in_sizes[0] / 256;
  int blocks = (B + EPB - 1) / EPB;

  hipLaunchKernelGGL(prep, dim3(11), dim3(256), 0, stream,
                     w1, bnp1, w2, bnp2, wr1, bnr1, wr2, bnr2,
                     wa1, bna1, wb1, bnb1, wc1, bnc1,
                     wa2, bna2, wb2, bnb2, wc2, bnc2, ws);

  hipLaunchKernelGGL(taunet, dim3(blocks), dim3(TPB), 0, stream,
                     x, ws, (float*)d_out, B);
}